// Round 7
// baseline (1582.931 us; speedup 1.0000x reference)
//
#include <hip/hip_runtime.h>

#define BB   16
#define SS   8192
#define DD   128
#define HH   256
#define NTOK (BB * SS)
#define TM   64
#define THREADS 512
#define LRATE 0.1f
#define EPSV  1e-5f
#define XCST 264   // XC stride in shorts: [x(128)|c(128)|pad8]
#define HST  264   // Hb stride in shorts

typedef short  bfrag __attribute__((ext_vector_type(8)));   // 8 bf16 = 4 VGPR (MFMA A/B frag)
typedef float  f32x4 __attribute__((ext_vector_type(4)));   // MFMA C/D frag
typedef unsigned short u16;

__device__ __forceinline__ u16 f2bf(float x) {
    unsigned u = __float_as_uint(x);
    unsigned r = (u + 0x7FFFu + ((u >> 16) & 1u)) >> 16;   // RTN-even
    return (u16)r;
}

// ---- weight prep: fp32 [K][N] -> bf16 transposed [N][K] in ws ----
// layout (shorts): W1t[256][128] @0, W2t[128][256] @32768, Wg1t[256][256] @65536, Wg2t[128][256] @131072
__global__ void prep_weights(const float* __restrict__ W1, const float* __restrict__ W2,
                             const float* __restrict__ Wg1, const float* __restrict__ Wg2,
                             u16* __restrict__ wsw) {
    int i = blockIdx.x * 256 + threadIdx.x;   // 0 .. 163839
    if (i < 32768) { int n = i >> 7, k = i & 127; wsw[i] = f2bf(W1[k * 256 + n]); return; }
    i -= 32768;
    if (i < 32768) { int n = i >> 8, k = i & 255; wsw[32768 + n * 256 + k] = f2bf(W2[k * 128 + n]); return; }
    i -= 32768;
    if (i < 65536) { int n = i >> 8, k = i & 255; wsw[65536 + n * 256 + k] = f2bf(Wg1[k * 256 + n]); return; }
    i -= 65536;
    { int n = i >> 8, k = i & 255; wsw[131072 + n * 256 + k] = f2bf(Wg2[k * 128 + n]); }
}

__global__ __launch_bounds__(THREADS, 4)
void refine_iter(const float* __restrict__ cur, const float* __restrict__ emb,
                 float* __restrict__ outp,
                 const u16* __restrict__ w1t, const u16* __restrict__ w2t,
                 const u16* __restrict__ wg1t, const u16* __restrict__ wg2t,
                 const float* __restrict__ b1, const float* __restrict__ lng,
                 const float* __restrict__ lnb, const float* __restrict__ b2,
                 const float* __restrict__ bg1, const float* __restrict__ bg2)
{
    __shared__ __align__(16) u16 XC[TM][XCST];   // [x | context] bf16
    __shared__ __align__(16) u16 Hb[TM][HST];    // H (phase-B input) then R (phase-D input)
    __shared__ float red1[TM][2];
    __shared__ float red2[TM][2];

    const int t    = threadIdx.x;
    const int g0   = blockIdx.x * TM;
    const int lane = t & 63;
    const int wid  = t >> 6;              // 8 waves
    const int rw   = wid & 3;             // row-tile (16 rows each)
    const int ch   = wid >> 2;            // column half
    const int l16  = lane & 15;
    const int lk8  = (lane >> 4) * 8;     // k-offset within a 32-chunk
    const int l4   = (lane >> 4) * 4;     // D-frag row offset
    const int r0   = rw * 16;             // wave's row base within tile

    // ---- stage x tile + context tile (fp32 -> bf16) into XC ----
    #pragma unroll
    for (int k = 0; k < 4; ++k) {
        const int f = t + k * THREADS;    // [0,2048)
        const int m = f >> 5;             // row 0..63
        const int o = (f & 31) * 4;
        const int gt = g0 + m;
        const int s  = gt & (SS - 1);
        const int rowbase = gt - s;
        const int sp = (s == 0) ? 1 : s - 1;
        const int sn = (s == SS - 1) ? (SS - 2) : s + 1;
        const float4 xv = *(const float4*)(cur + (size_t)gt * DD + o);
        const float4 av = *(const float4*)(cur + (size_t)(rowbase + sp) * DD + o);
        const float4 bv = *(const float4*)(cur + (size_t)(rowbase + sn) * DD + o);
        ushort4 xu; xu.x = f2bf(xv.x); xu.y = f2bf(xv.y); xu.z = f2bf(xv.z); xu.w = f2bf(xv.w);
        *(ushort4*)&XC[m][o] = xu;
        ushort4 cu;
        cu.x = f2bf(0.5f * (av.x + bv.x)); cu.y = f2bf(0.5f * (av.y + bv.y));
        cu.z = f2bf(0.5f * (av.z + bv.z)); cu.w = f2bf(0.5f * (av.w + bv.w));
        *(ushort4*)&XC[m][128 + o] = cu;
    }

    // ---- early prefetch: emb values needed by phase B (acc layout) ----
    float emb_pre[4][4];
    {
        const int n0b = ch * 64;
        #pragma unroll
        for (int ct = 0; ct < 4; ++ct)
            #pragma unroll
            for (int r = 0; r < 4; ++r)
                emb_pre[ct][r] = emb[(size_t)(g0 + r0 + l4 + r) * DD + n0b + ct * 16 + l16];
    }
    __syncthreads();

    const f32x4 zf = {0.f, 0.f, 0.f, 0.f};
    float mu[4], rs[4];

    // ================= Phase A: Y1 = X @ W1 + b1  (64x256, K=128) =================
    {
        const int n0 = ch * 128;
        f32x4 acc[8];
        #pragma unroll
        for (int ct = 0; ct < 8; ++ct) acc[ct] = zf;
        bfrag af[4];
        #pragma unroll
        for (int ks = 0; ks < 4; ++ks)
            af[ks] = *(const bfrag*)&XC[r0 + l16][ks * 32 + lk8];
        #pragma unroll
        for (int ct = 0; ct < 8; ++ct) {
            const u16* wp = w1t + (size_t)(n0 + ct * 16 + l16) * 128 + lk8;
            #pragma unroll
            for (int ks = 0; ks < 4; ++ks) {
                const bfrag bv = *(const bfrag*)(wp + ks * 32);
                acc[ct] = __builtin_amdgcn_mfma_f32_16x16x32_bf16(af[ks], bv, acc[ct], 0, 0, 0);
            }
        }
        // bias before LN stats
        #pragma unroll
        for (int ct = 0; ct < 8; ++ct) {
            const float bb = b1[n0 + ct * 16 + l16];
            #pragma unroll
            for (int r = 0; r < 4; ++r) acc[ct][r] += bb;
        }

        // ---- LN stats: 16-lane butterfly per row, cross-half via red ----
        #pragma unroll
        for (int r = 0; r < 4; ++r) {
            float a = 0.f, q = 0.f;
            #pragma unroll
            for (int ct = 0; ct < 8; ++ct) {
                const float v = acc[ct][r];
                a += v; q += v * v;
            }
            #pragma unroll
            for (int m = 1; m <= 8; m <<= 1) {
                a += __shfl_xor(a, m);
                q += __shfl_xor(q, m);
            }
            if (l16 == 0) {
                red1[r0 + l4 + r][ch] = a;
                red2[r0 + l4 + r][ch] = q;
            }
        }
        __syncthreads();
        #pragma unroll
        for (int r = 0; r < 4; ++r) {
            const int row = r0 + l4 + r;
            const float s1 = red1[row][0] + red1[row][1];
            const float s2 = red2[row][0] + red2[row][1];
            const float m_ = s1 * (1.f / (float)HH);
            mu[r] = m_;
            rs[r] = rsqrtf(s2 * (1.f / (float)HH) - m_ * m_ + EPSV);
        }

        // ---- normalize + affine + relu -> Hb (bf16) ----
        #pragma unroll
        for (int ct = 0; ct < 8; ++ct) {
            const int col = n0 + ct * 16 + l16;
            const float g = lng[col];
            const float b = lnb[col];
            #pragma unroll
            for (int r = 0; r < 4; ++r) {
                const float h = fmaxf((acc[ct][r] - mu[r]) * rs[r] * g + b, 0.f);
                Hb[r0 + l4 + r][col] = f2bf(h);
            }
        }
    }
    __syncthreads();

    // ================= Phase B: P = H @ W2 + b2 ; err = emb - P  (64x128, K=256) =================
    float errv[4][4];
    {
        const int n0 = ch * 64;
        f32x4 acc[4];
        #pragma unroll
        for (int ct = 0; ct < 4; ++ct) acc[ct] = zf;
        #pragma unroll
        for (int ks = 0; ks < 8; ++ks) {
            const bfrag a0 = *(const bfrag*)&Hb[r0 + l16][ks * 32 + lk8];
            #pragma unroll
            for (int ct = 0; ct < 4; ++ct) {
                const bfrag bv = *(const bfrag*)(w2t + (size_t)(n0 + ct * 16 + l16) * 256 + ks * 32 + lk8);
                acc[ct] = __builtin_amdgcn_mfma_f32_16x16x32_bf16(a0, bv, acc[ct], 0, 0, 0);
            }
        }
        #pragma unroll
        for (int ct = 0; ct < 4; ++ct) {
            const float bb = b2[n0 + ct * 16 + l16];
            #pragma unroll
            for (int r = 0; r < 4; ++r)
                errv[ct][r] = emb_pre[ct][r] - (acc[ct][r] + bb);
        }
    }

    // ================= Phase C: R = relu([X|C] @ Wg1 + bg1)  (64x256, K=256) =================
    {
        const int n0 = ch * 128;
        f32x4 acc[8];
        #pragma unroll
        for (int ct = 0; ct < 8; ++ct) acc[ct] = zf;
        #pragma unroll
        for (int ks = 0; ks < 8; ++ks) {
            const bfrag a0 = *(const bfrag*)&XC[r0 + l16][ks * 32 + lk8];
            #pragma unroll
            for (int ct = 0; ct < 8; ++ct) {
                const bfrag bv = *(const bfrag*)(wg1t + (size_t)(n0 + ct * 16 + l16) * 256 + ks * 32 + lk8);
                acc[ct] = __builtin_amdgcn_mfma_f32_16x16x32_bf16(a0, bv, acc[ct], 0, 0, 0);
            }
        }
        __syncthreads();   // all waves done reading Hb (phase B) before overwrite
        #pragma unroll
        for (int ct = 0; ct < 8; ++ct) {
            const float bb = bg1[n0 + ct * 16 + l16];
            #pragma unroll
            for (int r = 0; r < 4; ++r)
                Hb[r0 + l4 + r][n0 + ct * 16 + l16] = f2bf(fmaxf(acc[ct][r] + bb, 0.f));
        }
    }
    __syncthreads();

    // ================= Phase D: G = R @ Wg2 + bg2 ; out = x + LR*sigmoid(G)*err =================
    {
        const int n0 = ch * 64;
        f32x4 acc[4];
        #pragma unroll
        for (int ct = 0; ct < 4; ++ct) acc[ct] = zf;
        #pragma unroll
        for (int ks = 0; ks < 8; ++ks) {
            const bfrag a0 = *(const bfrag*)&Hb[r0 + l16][ks * 32 + lk8];
            #pragma unroll
            for (int ct = 0; ct < 4; ++ct) {
                const bfrag bv = *(const bfrag*)(wg2t + (size_t)(n0 + ct * 16 + l16) * 256 + ks * 32 + lk8);
                acc[ct] = __builtin_amdgcn_mfma_f32_16x16x32_bf16(a0, bv, acc[ct], 0, 0, 0);
            }
        }
        #pragma unroll
        for (int ct = 0; ct < 4; ++ct) {
            const float bb = bg2[n0 + ct * 16 + l16];
            #pragma unroll
            for (int r = 0; r < 4; ++r) {
                const int row = g0 + r0 + l4 + r;
                const int col = n0 + ct * 16 + l16;
                const float z = acc[ct][r] + bb;
                const float gate = 1.f / (1.f + __expf(-z));
                const float x = cur[(size_t)row * DD + col];
                outp[(size_t)row * DD + col] = x + LRATE * gate * errv[ct][r];
            }
        }
    }
}

extern "C" void kernel_launch(void* const* d_in, const int* in_sizes, int n_in,
                              void* d_out, int out_size, void* d_ws, size_t ws_size,
                              hipStream_t stream) {
    const float* emb = (const float*)d_in[0];
    const float* W1  = (const float*)d_in[1];
    const float* b1  = (const float*)d_in[2];
    const float* lng = (const float*)d_in[3];
    const float* lnb = (const float*)d_in[4];
    const float* W2  = (const float*)d_in[5];
    const float* b2  = (const float*)d_in[6];
    const float* Wg1 = (const float*)d_in[7];
    const float* bg1 = (const float*)d_in[8];
    const float* Wg2 = (const float*)d_in[9];
    const float* bg2 = (const float*)d_in[10];
    float* out = (float*)d_out;

    u16*   wsw  = (u16*)d_ws;                          // 320 KB bf16 transposed weights
    float* ping = (float*)((char*)d_ws + (1 << 20));   // 64 MB refined scratch

    const u16* w1t  = wsw;
    const u16* w2t  = wsw + 32768;
    const u16* wg1t = wsw + 65536;
    const u16* wg2t = wsw + 131072;

    prep_weights<<<640, 256, 0, stream>>>(W1, W2, Wg1, Wg2, wsw);

    const dim3 grid(NTOK / TM);
    const dim3 block(THREADS);
    // refined chain: emb -> out -> ping -> out -> ping -> out
    refine_iter<<<grid, block, 0, stream>>>(emb,  emb, out,  w1t, w2t, wg1t, wg2t, b1, lng, lnb, b2, bg1, bg2);
    refine_iter<<<grid, block, 0, stream>>>(out,  emb, ping, w1t, w2t, wg1t, wg2t, b1, lng, lnb, b2, bg1, bg2);
    refine_iter<<<grid, block, 0, stream>>>(ping, emb, out,  w1t, w2t, wg1t, wg2t, b1, lng, lnb, b2, bg1, bg2);
    refine_iter<<<grid, block, 0, stream>>>(out,  emb, ping, w1t, w2t, wg1t, wg2t, b1, lng, lnb, b2, bg1, bg2);
    refine_iter<<<grid, block, 0, stream>>>(ping, emb, out,  w1t, w2t, wg1t, wg2t, b1, lng, lnb, b2, bg1, bg2);
}

// Round 8
// 626.850 us; speedup vs baseline: 2.5252x; 2.5252x over previous
//
#include <hip/hip_runtime.h>

#define BB   16
#define SS   8192
#define DD   128
#define HH   256
#define NTOK (BB * SS)
#define TM   64
#define THREADS 256
#define LRATE 0.1f
#define EPSV  1e-5f
#define XCST 264   // XC stride in shorts: [x(128)|c(128)|pad8]
#define HST  264   // Hb stride in shorts

typedef short  bfrag __attribute__((ext_vector_type(8)));   // 8 bf16 = 4 VGPR (MFMA A/B frag)
typedef float  f32x4 __attribute__((ext_vector_type(4)));   // MFMA C/D frag
typedef unsigned short u16;

__device__ __forceinline__ u16 f2bf(float x) {
    unsigned u = __float_as_uint(x);
    unsigned r = (u + 0x7FFFu + ((u >> 16) & 1u)) >> 16;   // RTN-even
    return (u16)r;
}

// ---- weight prep: fp32 [K][N] -> bf16 transposed [N][K] in ws ----
// layout (shorts): W1t[256][128] @0, W2t[128][256] @32768, Wg1t[256][256] @65536, Wg2t[128][256] @131072
__global__ void prep_weights(const float* __restrict__ W1, const float* __restrict__ W2,
                             const float* __restrict__ Wg1, const float* __restrict__ Wg2,
                             u16* __restrict__ wsw) {
    int i = blockIdx.x * 256 + threadIdx.x;   // 0 .. 163839
    if (i < 32768) { int n = i >> 7, k = i & 127; wsw[i] = f2bf(W1[k * 256 + n]); return; }
    i -= 32768;
    if (i < 32768) { int n = i >> 8, k = i & 255; wsw[32768 + n * 256 + k] = f2bf(W2[k * 128 + n]); return; }
    i -= 32768;
    if (i < 65536) { int n = i >> 8, k = i & 255; wsw[65536 + n * 256 + k] = f2bf(Wg1[k * 256 + n]); return; }
    i -= 65536;
    { int n = i >> 8, k = i & 255; wsw[131072 + n * 256 + k] = f2bf(Wg2[k * 128 + n]); }
}

__global__ __launch_bounds__(THREADS, 2)
void refine_iter(const float* __restrict__ cur, const float* __restrict__ emb,
                 float* __restrict__ outp,
                 const u16* __restrict__ w1t, const u16* __restrict__ w2t,
                 const u16* __restrict__ wg1t, const u16* __restrict__ wg2t,
                 const float* __restrict__ b1, const float* __restrict__ lng,
                 const float* __restrict__ lnb, const float* __restrict__ b2,
                 const float* __restrict__ bg1, const float* __restrict__ bg2)
{
    __shared__ __align__(16) u16 XC[TM][XCST];   // [x | context] bf16
    __shared__ __align__(16) u16 Hb[TM][HST];    // H (phase-B input) then R (phase-D input)
    __shared__ float red1[TM][4];
    __shared__ float red2[TM][4];

    const int t    = threadIdx.x;
    const int g0   = blockIdx.x * TM;
    const int lane = t & 63;
    const int wid  = t >> 6;              // 4 waves; each owns ALL 64 rows x a column slice
    const int l16  = lane & 15;
    const int lk8  = (lane >> 4) * 8;     // k-offset within a 32-chunk
    const int l4   = (lane >> 4) * 4;     // D-frag row offset

    // ---- stage x tile + context tile (fp32 -> bf16) into XC ----
    #pragma unroll
    for (int k = 0; k < 8; ++k) {
        const int f = t + k * THREADS;    // [0,2048)
        const int m = f >> 5;             // row 0..63
        const int o = (f & 31) * 4;
        const int gt = g0 + m;
        const int s  = gt & (SS - 1);
        const int rowbase = gt - s;
        const int sp = (s == 0) ? 1 : s - 1;
        const int sn = (s == SS - 1) ? (SS - 2) : s + 1;
        const float4 xv = *(const float4*)(cur + (size_t)gt * DD + o);
        const float4 av = *(const float4*)(cur + (size_t)(rowbase + sp) * DD + o);
        const float4 bv = *(const float4*)(cur + (size_t)(rowbase + sn) * DD + o);
        ushort4 xu; xu.x = f2bf(xv.x); xu.y = f2bf(xv.y); xu.z = f2bf(xv.z); xu.w = f2bf(xv.w);
        *(ushort4*)&XC[m][o] = xu;
        ushort4 cu;
        cu.x = f2bf(0.5f * (av.x + bv.x)); cu.y = f2bf(0.5f * (av.y + bv.y));
        cu.z = f2bf(0.5f * (av.z + bv.z)); cu.w = f2bf(0.5f * (av.w + bv.w));
        *(ushort4*)&XC[m][128 + o] = cu;
    }

    // ---- early prefetch: emb values needed by phase B (acc layout) ----
    float emb_pre[4][2][4];
    {
        const int n0b = wid * 32;
        #pragma unroll
        for (int rt = 0; rt < 4; ++rt)
            #pragma unroll
            for (int ct = 0; ct < 2; ++ct)
                #pragma unroll
                for (int r = 0; r < 4; ++r)
                    emb_pre[rt][ct][r] = emb[(size_t)(g0 + rt * 16 + l4 + r) * DD + n0b + ct * 16 + l16];
    }
    __syncthreads();

    const f32x4 zf = {0.f, 0.f, 0.f, 0.f};
    float mu[4][4], rs[4][4];

    // ================= Phase A: Y1 = X @ W1 + b1  (64x256, K=128) =================
    {
        const int n0 = wid * 64;
        f32x4 acc[4][4];   // [rt][ct]
        #pragma unroll
        for (int rt = 0; rt < 4; ++rt)
            #pragma unroll
            for (int ct = 0; ct < 4; ++ct) acc[rt][ct] = zf;
        #pragma unroll
        for (int h = 0; h < 2; ++h) {        // ct-pairs
            bfrag wb[8];                     // i(2) x ks(4), batched
            #pragma unroll
            for (int i = 0; i < 2; ++i)
                #pragma unroll
                for (int ks = 0; ks < 4; ++ks)
                    wb[i * 4 + ks] = *(const bfrag*)(w1t + (size_t)(n0 + (h * 2 + i) * 16 + l16) * 128 + ks * 32 + lk8);
            __builtin_amdgcn_sched_barrier(0);   // pin: all 8 loads issued before MFMA burst
            #pragma unroll
            for (int ks = 0; ks < 4; ++ks) {
                bfrag af[4];
                #pragma unroll
                for (int rt = 0; rt < 4; ++rt)
                    af[rt] = *(const bfrag*)&XC[rt * 16 + l16][ks * 32 + lk8];
                #pragma unroll
                for (int i = 0; i < 2; ++i)
                    #pragma unroll
                    for (int rt = 0; rt < 4; ++rt)
                        acc[rt][h * 2 + i] = __builtin_amdgcn_mfma_f32_16x16x32_bf16(af[rt], wb[i * 4 + ks], acc[rt][h * 2 + i], 0, 0, 0);
            }
        }
        // bias before LN stats
        #pragma unroll
        for (int ct = 0; ct < 4; ++ct) {
            const float bb = b1[n0 + ct * 16 + l16];
            #pragma unroll
            for (int rt = 0; rt < 4; ++rt)
                #pragma unroll
                for (int r = 0; r < 4; ++r) acc[rt][ct][r] += bb;
        }

        // ---- LN stats: 16-lane butterfly per row, cross-wave via red ----
        #pragma unroll
        for (int rt = 0; rt < 4; ++rt)
            #pragma unroll
            for (int r = 0; r < 4; ++r) {
                float a = 0.f, q = 0.f;
                #pragma unroll
                for (int ct = 0; ct < 4; ++ct) {
                    const float v = acc[rt][ct][r];
                    a += v; q += v * v;
                }
                #pragma unroll
                for (int m = 1; m <= 8; m <<= 1) {
                    a += __shfl_xor(a, m);
                    q += __shfl_xor(q, m);
                }
                if (l16 == 0) {
                    red1[rt * 16 + l4 + r][wid] = a;
                    red2[rt * 16 + l4 + r][wid] = q;
                }
            }
        __syncthreads();
        #pragma unroll
        for (int rt = 0; rt < 4; ++rt)
            #pragma unroll
            for (int r = 0; r < 4; ++r) {
                const int row = rt * 16 + l4 + r;
                const float4 s1v = *(const float4*)&red1[row][0];
                const float4 s2v = *(const float4*)&red2[row][0];
                const float s1 = s1v.x + s1v.y + s1v.z + s1v.w;
                const float s2 = s2v.x + s2v.y + s2v.z + s2v.w;
                const float m_ = s1 * (1.f / (float)HH);
                mu[rt][r] = m_;
                rs[rt][r] = rsqrtf(s2 * (1.f / (float)HH) - m_ * m_ + EPSV);
            }

        // ---- normalize + affine + relu -> Hb (bf16) ----
        #pragma unroll
        for (int ct = 0; ct < 4; ++ct) {
            const int col = n0 + ct * 16 + l16;
            const float g = lng[col];
            const float b = lnb[col];
            #pragma unroll
            for (int rt = 0; rt < 4; ++rt)
                #pragma unroll
                for (int r = 0; r < 4; ++r) {
                    const float h = fmaxf((acc[rt][ct][r] - mu[rt][r]) * rs[rt][r] * g + b, 0.f);
                    Hb[rt * 16 + l4 + r][col] = f2bf(h);
                }
        }
    }
    __syncthreads();

    // ================= Phase B: P = H @ W2 + b2 ; err = emb - P  (64x128, K=256) =================
    float errv[4][2][4];
    {
        const int n0 = wid * 32;
        f32x4 acc[4][2];
        #pragma unroll
        for (int rt = 0; rt < 4; ++rt) { acc[rt][0] = zf; acc[rt][1] = zf; }
        bfrag wb[16];                        // ct(2) x ks(8), batched
        #pragma unroll
        for (int ct = 0; ct < 2; ++ct)
            #pragma unroll
            for (int ks = 0; ks < 8; ++ks)
                wb[ct * 8 + ks] = *(const bfrag*)(w2t + (size_t)(n0 + ct * 16 + l16) * 256 + ks * 32 + lk8);
        __builtin_amdgcn_sched_barrier(0);
        #pragma unroll
        for (int ks = 0; ks < 8; ++ks) {
            bfrag af[4];
            #pragma unroll
            for (int rt = 0; rt < 4; ++rt)
                af[rt] = *(const bfrag*)&Hb[rt * 16 + l16][ks * 32 + lk8];
            #pragma unroll
            for (int ct = 0; ct < 2; ++ct)
                #pragma unroll
                for (int rt = 0; rt < 4; ++rt)
                    acc[rt][ct] = __builtin_amdgcn_mfma_f32_16x16x32_bf16(af[rt], wb[ct * 8 + ks], acc[rt][ct], 0, 0, 0);
        }
        #pragma unroll
        for (int ct = 0; ct < 2; ++ct) {
            const float bb = b2[n0 + ct * 16 + l16];
            #pragma unroll
            for (int rt = 0; rt < 4; ++rt)
                #pragma unroll
                for (int r = 0; r < 4; ++r)
                    errv[rt][ct][r] = emb_pre[rt][ct][r] - (acc[rt][ct][r] + bb);
        }
    }

    // ================= Phase C: R = relu([X|C] @ Wg1 + bg1)  (64x256, K=256) =================
    {
        const int n0 = wid * 64;
        f32x4 acc[4][4];
        #pragma unroll
        for (int rt = 0; rt < 4; ++rt)
            #pragma unroll
            for (int ct = 0; ct < 4; ++ct) acc[rt][ct] = zf;
        #pragma unroll
        for (int h = 0; h < 2; ++h) {
            bfrag wb[16];                    // i(2) x ks(8), batched
            #pragma unroll
            for (int i = 0; i < 2; ++i)
                #pragma unroll
                for (int ks = 0; ks < 8; ++ks)
                    wb[i * 8 + ks] = *(const bfrag*)(wg1t + (size_t)(n0 + (h * 2 + i) * 16 + l16) * 256 + ks * 32 + lk8);
            __builtin_amdgcn_sched_barrier(0);
            #pragma unroll
            for (int ks = 0; ks < 8; ++ks) {
                bfrag af[4];
                #pragma unroll
                for (int rt = 0; rt < 4; ++rt)
                    af[rt] = *(const bfrag*)&XC[rt * 16 + l16][ks * 32 + lk8];
                #pragma unroll
                for (int i = 0; i < 2; ++i)
                    #pragma unroll
                    for (int rt = 0; rt < 4; ++rt)
                        acc[rt][h * 2 + i] = __builtin_amdgcn_mfma_f32_16x16x32_bf16(af[rt], wb[i * 8 + ks], acc[rt][h * 2 + i], 0, 0, 0);
            }
        }
        __syncthreads();   // all waves done reading Hb (phase B) before overwrite
        #pragma unroll
        for (int ct = 0; ct < 4; ++ct) {
            const float bb = bg1[n0 + ct * 16 + l16];
            #pragma unroll
            for (int rt = 0; rt < 4; ++rt)
                #pragma unroll
                for (int r = 0; r < 4; ++r)
                    Hb[rt * 16 + l4 + r][n0 + ct * 16 + l16] = f2bf(fmaxf(acc[rt][ct][r] + bb, 0.f));
        }
    }
    __syncthreads();

    // ================= Phase D: G = R @ Wg2 + bg2 ; out = x + LR*sigmoid(G)*err =================
    {
        const int n0 = wid * 32;
        f32x4 acc[4][2];
        #pragma unroll
        for (int rt = 0; rt < 4; ++rt) { acc[rt][0] = zf; acc[rt][1] = zf; }
        bfrag wb[16];
        #pragma unroll
        for (int ct = 0; ct < 2; ++ct)
            #pragma unroll
            for (int ks = 0; ks < 8; ++ks)
                wb[ct * 8 + ks] = *(const bfrag*)(wg2t + (size_t)(n0 + ct * 16 + l16) * 256 + ks * 32 + lk8);
        __builtin_amdgcn_sched_barrier(0);
        #pragma unroll
        for (int ks = 0; ks < 8; ++ks) {
            bfrag af[4];
            #pragma unroll
            for (int rt = 0; rt < 4; ++rt)
                af[rt] = *(const bfrag*)&Hb[rt * 16 + l16][ks * 32 + lk8];
            #pragma unroll
            for (int ct = 0; ct < 2; ++ct)
                #pragma unroll
                for (int rt = 0; rt < 4; ++rt)
                    acc[rt][ct] = __builtin_amdgcn_mfma_f32_16x16x32_bf16(af[rt], wb[ct * 8 + ks], acc[rt][ct], 0, 0, 0);
        }
        #pragma unroll
        for (int ct = 0; ct < 2; ++ct) {
            const float bb = bg2[n0 + ct * 16 + l16];
            #pragma unroll
            for (int rt = 0; rt < 4; ++rt)
                #pragma unroll
                for (int r = 0; r < 4; ++r) {
                    const int row = g0 + rt * 16 + l4 + r;
                    const int col = n0 + ct * 16 + l16;
                    const float z = acc[rt][ct][r] + bb;
                    const float gate = 1.f / (1.f + __expf(-z));
                    const float x = cur[(size_t)row * DD + col];
                    outp[(size_t)row * DD + col] = x + LRATE * gate * errv[rt][ct][r];
                }
        }
    }
}

extern "C" void kernel_launch(void* const* d_in, const int* in_sizes, int n_in,
                              void* d_out, int out_size, void* d_ws, size_t ws_size,
                              hipStream_t stream) {
    const float* emb = (const float*)d_in[0];
    const float* W1  = (const float*)d_in[1];
    const float* b1  = (const float*)d_in[2];
    const float* lng = (const float*)d_in[3];
    const float* lnb = (const float*)d_in[4];
    const float* W2  = (const float*)d_in[5];
    const float* b2  = (const float*)d_in[6];
    const float* Wg1 = (const float*)d_in[7];
    const float* bg1 = (const float*)d_in[8];
    const float* Wg2 = (const float*)d_in[9];
    const float* bg2 = (const float*)d_in[10];
    float* out = (float*)d_out;

    u16*   wsw  = (u16*)d_ws;                          // 320 KB bf16 transposed weights
    float* ping = (float*)((char*)d_ws + (1 << 20));   // 64 MB refined scratch

    const u16* w1t  = wsw;
    const u16* w2t  = wsw + 32768;
    const u16* wg1t = wsw + 65536;
    const u16* wg2t = wsw + 131072;

    prep_weights<<<640, 256, 0, stream>>>(W1, W2, Wg1, Wg2, wsw);

    const dim3 grid(NTOK / TM);
    const dim3 block(THREADS);
    // refined chain: emb -> out -> ping -> out -> ping -> out
    refine_iter<<<grid, block, 0, stream>>>(emb,  emb, out,  w1t, w2t, wg1t, wg2t, b1, lng, lnb, b2, bg1, bg2);
    refine_iter<<<grid, block, 0, stream>>>(out,  emb, ping, w1t, w2t, wg1t, wg2t, b1, lng, lnb, b2, bg1, bg2);
    refine_iter<<<grid, block, 0, stream>>>(ping, emb, out,  w1t, w2t, wg1t, wg2t, b1, lng, lnb, b2, bg1, bg2);
    refine_iter<<<grid, block, 0, stream>>>(out,  emb, ping, w1t, w2t, wg1t, wg2t, b1, lng, lnb, b2, bg1, bg2);
    refine_iter<<<grid, block, 0, stream>>>(ping, emb, out,  w1t, w2t, wg1t, wg2t, b1, lng, lnb, b2, bg1, bg2);
}